// Round 2
// baseline (252.041 us; speedup 1.0000x reference)
//
#include <hip/hip_runtime.h>
#include <hip/hip_bf16.h>

// NT-Xent (SimCLR) fused loss, MI355X gfx950. Round 2: exploit sim symmetry
// (upper-triangle tiles only, each off-diag tile feeds row sums AND col sums)
// and fuse the final reduction into the tile kernel via last-block ticket.
//
// ws layout: [S: N floats][pos: N floats][ticket: 1 uint (padded to 4 floats)]
//            [zn: N*D bf16]

#define N_TOT 8192
#define BATCH 4096
#define DIM   256
#define BK    64
#define NT_TILES 64                  // 8192 / 128
#define TOTAL_BLOCKS (64 * 33)       // wrapped upper-triangle enumeration

typedef short bf16x8 __attribute__((ext_vector_type(8)));
typedef float f32x4  __attribute__((ext_vector_type(4)));

__device__ __forceinline__ void load_lds16(const void* g, void* l) {
  __builtin_amdgcn_global_load_lds(
      (const __attribute__((address_space(1))) unsigned int*)g,
      (__attribute__((address_space(3))) unsigned int*)l,
      16, 0, 0);
}

__device__ __forceinline__ unsigned short f32_to_bf16(float f) {
  unsigned int u = __float_as_uint(f);
  u += 0x7fff + ((u >> 16) & 1);   // RNE
  return (unsigned short)(u >> 16);
}

// One wave per row: 64 lanes x float4 = 256 elements. Zeros S and the ticket.
__global__ __launch_bounds__(256) void normalize_kernel(
    const float* __restrict__ z, unsigned short* __restrict__ zn,
    float* __restrict__ S, unsigned int* __restrict__ ticket) {
  const int wave = threadIdx.x >> 6;
  const int lane = threadIdx.x & 63;
  const int row  = blockIdx.x * 4 + wave;
  float4 v = ((const float4*)(z + (size_t)row * DIM))[lane];
  float ss = v.x * v.x + v.y * v.y + v.z * v.z + v.w * v.w;
#pragma unroll
  for (int m = 1; m <= 32; m <<= 1) ss += __shfl_xor(ss, m);
  float inv = 1.0f / sqrtf(ss);
  ushort4 o;
  o.x = f32_to_bf16(v.x * inv);
  o.y = f32_to_bf16(v.y * inv);
  o.z = f32_to_bf16(v.z * inv);
  o.w = f32_to_bf16(v.w * inv);
  ((ushort4*)(zn + (size_t)row * DIM))[lane] = o;
  if (threadIdx.x < 4) S[blockIdx.x * 4 + threadIdx.x] = 0.0f;
  if (blockIdx.x == 0 && threadIdx.x == 0) *ticket = 0u;
}

// Upper-triangle 128x128 tiles of sim = zn*zn^T*10, fused exp + row/col sums.
// Grid: (33, 64). j = blockIdx.x in [0,32], rb_raw = blockIdx.y.
// cb_raw = (rb_raw + j) % 64; j==32 only processed for rb_raw < 32.
// Last finished block computes loss = mean(log S - pos).
__global__ __launch_bounds__(256, 2) void simclr_tile_kernel(
    const unsigned short* __restrict__ zn, float* __restrict__ S,
    float* __restrict__ pos, unsigned int* __restrict__ ticket,
    float* __restrict__ out) {
  const int j = blockIdx.x, rb_raw = blockIdx.y;
  const int tid = threadIdx.x;
  const int wave = tid >> 6, lane = tid & 63;
  const int wm = wave >> 1, wn = wave & 1;      // wave quadrant (2x2)
  const int c = lane & 15, quad = lane >> 4;    // MFMA lane coords

  const bool skip = (j == 32) && (rb_raw >= 32);

  __shared__ alignas(16) unsigned short As[128 * BK];
  __shared__ alignas(16) unsigned short Bs[128 * BK];

  if (!skip) {
    int cb_raw = rb_raw + j;
    if (cb_raw >= NT_TILES) cb_raw -= NT_TILES;
    const int rb = (cb_raw < rb_raw) ? cb_raw : rb_raw;
    const int cb = (cb_raw < rb_raw) ? rb_raw : cb_raw;
    const bool isdiag = (j == 0);

    f32x4 acc[4][4];
#pragma unroll
    for (int i = 0; i < 4; ++i)
#pragma unroll
      for (int jj = 0; jj < 4; ++jj) acc[i][jj] = (f32x4){0.f, 0.f, 0.f, 0.f};

    // Staging: per issue a wave writes 8 rows x 64 bf16; lane l -> row
    // +(l>>3), LDS chunk (l&7); fetches global chunk (l&7)^(l>>3) (swizzle).
    const int srow   = lane >> 3;
    const int schunk = (lane & 7) ^ srow;
    const size_t a_row0 = (size_t)rb * 128;
    const size_t b_row0 = (size_t)cb * 128;

#pragma unroll
    for (int kb = 0; kb < DIM / BK; ++kb) {
#pragma unroll
      for (int t = 0; t < 4; ++t) {
        const int rloc = wave * 32 + t * 8 + srow;
        load_lds16(zn + (a_row0 + rloc) * DIM + kb * BK + schunk * 8,
                   As + rloc * BK + (lane & 7) * 8);
        load_lds16(zn + (b_row0 + rloc) * DIM + kb * BK + schunk * 8,
                   Bs + rloc * BK + (lane & 7) * 8);
      }
      __syncthreads();

#pragma unroll
      for (int kk = 0; kk < BK / 32; ++kk) {
        const int kc = kk * 4 + quad;
        const int sl = (kc ^ (c & 7)) * 8;        // de-swizzled elem offset
        bf16x8 af[4], bfr[4];
#pragma unroll
        for (int f = 0; f < 4; ++f) {
          af[f]  = *(const bf16x8*)(As + (wm * 64 + f * 16 + c) * BK + sl);
          bfr[f] = *(const bf16x8*)(Bs + (wn * 64 + f * 16 + c) * BK + sl);
        }
#pragma unroll
        for (int fm = 0; fm < 4; ++fm)
#pragma unroll
          for (int fn = 0; fn < 4; ++fn)
            acc[fm][fn] = __builtin_amdgcn_mfma_f32_16x16x32_bf16(
                af[fm], bfr[fn], acc[fm][fn], 0, 0, 0);
      }
      __syncthreads();
    }

    // Epilogue. C/D layout: row = quad*4 + reg, col = lane&15 per 16x16 frag.
    float cs[4] = {0.f, 0.f, 0.f, 0.f};          // per-lane column partials
#pragma unroll
    for (int fm = 0; fm < 4; ++fm) {
#pragma unroll
      for (int r = 0; r < 4; ++r) {
        const int grow = rb * 128 + wm * 64 + fm * 16 + quad * 4 + r;
        float s = 0.f;
#pragma unroll
        for (int fn = 0; fn < 4; ++fn) {
          const int gcol = cb * 128 + wn * 64 + fn * 16 + c;
          const float logit = acc[fm][fn][r] * 10.0f;
          float e = __expf(logit);
          if (isdiag && gcol == grow) e = 0.f;   // exclude self-similarity
          if (!isdiag && gcol == grow + BATCH) { // partner pair (i, i+B)
            __hip_atomic_store(&pos[grow], logit, __ATOMIC_RELAXED,
                               __HIP_MEMORY_SCOPE_AGENT);
            __hip_atomic_store(&pos[gcol], logit, __ATOMIC_RELAXED,
                               __HIP_MEMORY_SCOPE_AGENT);
          }
          s += e;
          cs[fn] += e;
        }
        s += __shfl_xor(s, 1);
        s += __shfl_xor(s, 2);
        s += __shfl_xor(s, 4);
        s += __shfl_xor(s, 8);
        if (c == 0) atomicAdd(&S[grow], s);
      }
    }
    if (!isdiag) {
      // column sums -> S[col] (transpose contribution)
#pragma unroll
      for (int fn = 0; fn < 4; ++fn) {
        cs[fn] += __shfl_xor(cs[fn], 16);
        cs[fn] += __shfl_xor(cs[fn], 32);
      }
      if (quad == 0) {
#pragma unroll
        for (int fn = 0; fn < 4; ++fn)
          atomicAdd(&S[cb * 128 + wn * 64 + fn * 16 + c], cs[fn]);
      }
    }
  }

  // Last-block-done finalize: loss = mean(log S_i - pos_i)
  __threadfence();
  __shared__ bool amLast;
  if (tid == 0)
    amLast = (atomicAdd(ticket, 1u) == TOTAL_BLOCKS - 1);
  __syncthreads();
  if (amLast) {
    __threadfence();
    float a = 0.f;
    for (int i = tid; i < N_TOT; i += 256) {
      float Sv = __hip_atomic_load(&S[i], __ATOMIC_RELAXED,
                                   __HIP_MEMORY_SCOPE_AGENT);
      float pv = __hip_atomic_load(&pos[i], __ATOMIC_RELAXED,
                                   __HIP_MEMORY_SCOPE_AGENT);
      a += __logf(Sv) - pv;
    }
#pragma unroll
    for (int m = 1; m <= 32; m <<= 1) a += __shfl_xor(a, m);
    __shared__ float red[4];
    if ((tid & 63) == 0) red[tid >> 6] = a;
    __syncthreads();
    if (tid == 0)
      out[0] = (red[0] + red[1] + red[2] + red[3]) * (1.0f / (float)N_TOT);
  }
}

extern "C" void kernel_launch(void* const* d_in, const int* in_sizes, int n_in,
                              void* d_out, int out_size, void* d_ws,
                              size_t ws_size, hipStream_t stream) {
  const float* z = (const float*)d_in[0];
  float* out = (float*)d_out;
  char* ws = (char*)d_ws;
  float* S = (float*)ws;                                       // N floats
  float* pos = (float*)(ws + N_TOT * sizeof(float));           // N floats
  unsigned int* ticket = (unsigned int*)(ws + 2 * N_TOT * sizeof(float));
  unsigned short* zn =
      (unsigned short*)(ws + 2 * N_TOT * sizeof(float) + 16);  // N*D bf16

  normalize_kernel<<<N_TOT / 4, 256, 0, stream>>>(z, zn, S, ticket);
  dim3 grid(33, NT_TILES);
  simclr_tile_kernel<<<grid, 256, 0, stream>>>(zn, S, pos, ticket, out);
}

// Round 3
// 97.620 us; speedup vs baseline: 2.5819x; 2.5819x over previous
//
#include <hip/hip_runtime.h>
#include <hip/hip_bf16.h>

// NT-Xent (SimCLR) fused loss, MI355X gfx950. Round 3: keep round-2's
// upper-triangle symmetry (halved MFMA work, verified absmax 0.0) but revert
// the fence/ticket fused finalize, which stalled every block (~150us idle).
// Sync semantics are exactly round 1's: plain atomicAdd into S, plain stores
// into pos, separate finalize kernel (stream order guarantees visibility).
//
// ws layout: [S: N floats][pos: N floats][zn: N*D bf16]

#define N_TOT 8192
#define BATCH 4096
#define DIM   256
#define BK    64
#define NT_TILES 64                  // 8192 / 128

typedef short bf16x8 __attribute__((ext_vector_type(8)));
typedef float f32x4  __attribute__((ext_vector_type(4)));

__device__ __forceinline__ void load_lds16(const void* g, void* l) {
  __builtin_amdgcn_global_load_lds(
      (const __attribute__((address_space(1))) unsigned int*)g,
      (__attribute__((address_space(3))) unsigned int*)l,
      16, 0, 0);
}

__device__ __forceinline__ unsigned short f32_to_bf16(float f) {
  unsigned int u = __float_as_uint(f);
  u += 0x7fff + ((u >> 16) & 1);   // RNE
  return (unsigned short)(u >> 16);
}

// One wave per row: 64 lanes x float4 = 256 elements. Also zeros S.
__global__ __launch_bounds__(256) void normalize_kernel(
    const float* __restrict__ z, unsigned short* __restrict__ zn,
    float* __restrict__ S) {
  const int wave = threadIdx.x >> 6;
  const int lane = threadIdx.x & 63;
  const int row  = blockIdx.x * 4 + wave;
  float4 v = ((const float4*)(z + (size_t)row * DIM))[lane];
  float ss = v.x * v.x + v.y * v.y + v.z * v.z + v.w * v.w;
#pragma unroll
  for (int m = 1; m <= 32; m <<= 1) ss += __shfl_xor(ss, m);
  float inv = 1.0f / sqrtf(ss);
  ushort4 o;
  o.x = f32_to_bf16(v.x * inv);
  o.y = f32_to_bf16(v.y * inv);
  o.z = f32_to_bf16(v.z * inv);
  o.w = f32_to_bf16(v.w * inv);
  ((ushort4*)(zn + (size_t)row * DIM))[lane] = o;
  if (threadIdx.x < 4) S[blockIdx.x * 4 + threadIdx.x] = 0.0f;
}

// Upper-triangle 128x128 tiles of sim = zn*zn^T*10, fused exp + row/col sums.
// Grid (33, 64): j = blockIdx.x in [0,32], rb_raw = blockIdx.y.
// cb_raw = (rb_raw + j) % 64; j==32 only for rb_raw < 32 (each unordered
// pair exactly once: circular distance d<=31 appears at j=d only).
__global__ __launch_bounds__(256, 2) void simclr_tile_kernel(
    const unsigned short* __restrict__ zn, float* __restrict__ S,
    float* __restrict__ pos) {
  const int j = blockIdx.x, rb_raw = blockIdx.y;
  if (j == 32 && rb_raw >= 32) return;

  const int tid = threadIdx.x;
  const int wave = tid >> 6, lane = tid & 63;
  const int wm = wave >> 1, wn = wave & 1;      // wave quadrant (2x2)
  const int c = lane & 15, quad = lane >> 4;    // MFMA lane coords

  int cb_raw = rb_raw + j;
  if (cb_raw >= NT_TILES) cb_raw -= NT_TILES;
  const int rb = (cb_raw < rb_raw) ? cb_raw : rb_raw;
  const int cb = (cb_raw < rb_raw) ? rb_raw : cb_raw;
  const bool isdiag = (j == 0);

  __shared__ alignas(16) unsigned short As[128 * BK];
  __shared__ alignas(16) unsigned short Bs[128 * BK];

  f32x4 acc[4][4];
#pragma unroll
  for (int i = 0; i < 4; ++i)
#pragma unroll
    for (int jj = 0; jj < 4; ++jj) acc[i][jj] = (f32x4){0.f, 0.f, 0.f, 0.f};

  // Staging: per issue a wave writes 8 rows x 64 bf16; lane l -> row +(l>>3),
  // LDS chunk (l&7); fetches global chunk (l&7)^(l>>3) (XOR swizzle so the
  // ds_read_b128 fragment reads are conflict-free; measured 0 conflicts).
  const int srow   = lane >> 3;
  const int schunk = (lane & 7) ^ srow;
  const size_t a_row0 = (size_t)rb * 128;
  const size_t b_row0 = (size_t)cb * 128;

#pragma unroll
  for (int kb = 0; kb < DIM / BK; ++kb) {
#pragma unroll
    for (int t = 0; t < 4; ++t) {
      const int rloc = wave * 32 + t * 8 + srow;
      load_lds16(zn + (a_row0 + rloc) * DIM + kb * BK + schunk * 8,
                 As + rloc * BK + (lane & 7) * 8);
      load_lds16(zn + (b_row0 + rloc) * DIM + kb * BK + schunk * 8,
                 Bs + rloc * BK + (lane & 7) * 8);
    }
    __syncthreads();

#pragma unroll
    for (int kk = 0; kk < BK / 32; ++kk) {
      const int kc = kk * 4 + quad;
      const int sl = (kc ^ (c & 7)) * 8;          // de-swizzled elem offset
      bf16x8 af[4], bfr[4];
#pragma unroll
      for (int f = 0; f < 4; ++f) {
        af[f]  = *(const bf16x8*)(As + (wm * 64 + f * 16 + c) * BK + sl);
        bfr[f] = *(const bf16x8*)(Bs + (wn * 64 + f * 16 + c) * BK + sl);
      }
#pragma unroll
      for (int fm = 0; fm < 4; ++fm)
#pragma unroll
        for (int fn = 0; fn < 4; ++fn)
          acc[fm][fn] = __builtin_amdgcn_mfma_f32_16x16x32_bf16(
              af[fm], bfr[fn], acc[fm][fn], 0, 0, 0);
    }
    __syncthreads();
  }

  // Epilogue. C/D layout: row = quad*4 + reg, col = lane&15 per 16x16 frag.
  float cs[4] = {0.f, 0.f, 0.f, 0.f};            // per-lane column partials
#pragma unroll
  for (int fm = 0; fm < 4; ++fm) {
#pragma unroll
    for (int r = 0; r < 4; ++r) {
      const int grow = rb * 128 + wm * 64 + fm * 16 + quad * 4 + r;
      float s = 0.f;
#pragma unroll
      for (int fn = 0; fn < 4; ++fn) {
        const int gcol = cb * 128 + wn * 64 + fn * 16 + c;
        const float logit = acc[fm][fn][r] * 10.0f;
        float e = __expf(logit);
        if (isdiag && gcol == grow) e = 0.f;     // exclude self-similarity
        if (!isdiag && gcol == grow + BATCH) {   // partner pair (i, i+B):
          pos[grow] = logit;                     // unique writer per element
          pos[gcol] = logit;                     // sim symmetric -> same value
        }
        s += e;
        cs[fn] += e;
      }
      s += __shfl_xor(s, 1);
      s += __shfl_xor(s, 2);
      s += __shfl_xor(s, 4);
      s += __shfl_xor(s, 8);
      if (c == 0) atomicAdd(&S[grow], s);
    }
  }
  if (!isdiag) {
    // column sums -> S[col] (transpose contribution of this tile)
#pragma unroll
    for (int fn = 0; fn < 4; ++fn) {
      cs[fn] += __shfl_xor(cs[fn], 16);
      cs[fn] += __shfl_xor(cs[fn], 32);
    }
    if (quad == 0) {
#pragma unroll
      for (int fn = 0; fn < 4; ++fn)
        atomicAdd(&S[cb * 128 + wn * 64 + fn * 16 + c], cs[fn]);
    }
  }
}

// loss = mean(log(S_i) - pos_i)
__global__ __launch_bounds__(1024) void finalize_kernel(
    const float* __restrict__ S, const float* __restrict__ pos,
    float* __restrict__ out) {
  const int tid = threadIdx.x;
  float a = 0.f;
  for (int i = tid; i < N_TOT; i += 1024) a += __logf(S[i]) - pos[i];
#pragma unroll
  for (int m = 1; m <= 32; m <<= 1) a += __shfl_xor(a, m);
  __shared__ float red[16];
  if ((tid & 63) == 0) red[tid >> 6] = a;
  __syncthreads();
  if (tid < 16) {
    float v = red[tid];
    v += __shfl_xor(v, 1);
    v += __shfl_xor(v, 2);
    v += __shfl_xor(v, 4);
    v += __shfl_xor(v, 8);
    if (tid == 0) out[0] = v * (1.0f / (float)N_TOT);
  }
}

extern "C" void kernel_launch(void* const* d_in, const int* in_sizes, int n_in,
                              void* d_out, int out_size, void* d_ws,
                              size_t ws_size, hipStream_t stream) {
  const float* z = (const float*)d_in[0];
  float* out = (float*)d_out;
  char* ws = (char*)d_ws;
  float* S = (float*)ws;                                   // N floats
  float* pos = (float*)(ws + N_TOT * sizeof(float));       // N floats
  unsigned short* zn =
      (unsigned short*)(ws + 2 * N_TOT * sizeof(float));   // N*D bf16

  normalize_kernel<<<N_TOT / 4, 256, 0, stream>>>(z, zn, S);
  dim3 grid(33, NT_TILES);
  simclr_tile_kernel<<<grid, 256, 0, stream>>>(zn, S, pos);
  finalize_kernel<<<1, 1024, 0, stream>>>(S, pos, out);
}